// Round 1
// baseline (280.540 us; speedup 1.0000x reference)
//
#include <hip/hip_runtime.h>

#define NBLOCKS 2048
#define NTHREADS 256

__global__ __launch_bounds__(NTHREADS) void wmse_partial_kernel(
    const float4* __restrict__ pred4,
    const int4* __restrict__ lab4,
    const float* __restrict__ weights,
    double* __restrict__ partials,
    int n4)
{
    __shared__ float w[16];
    if (threadIdx.x < 10) w[threadIdx.x] = weights[threadIdx.x];
    __syncthreads();

    double acc = 0.0;
    int idx = blockIdx.x * NTHREADS + threadIdx.x;
    const int stride = NBLOCKS * NTHREADS;

    for (int i = idx; i < n4; i += stride) {
        float4 p = pred4[i];
        int4 l = lab4[i];
        float d0 = p.x - (float)l.x;
        float d1 = p.y - (float)l.y;
        float d2 = p.z - (float)l.z;
        float d3 = p.w - (float)l.w;
        float s = w[l.x] * d0 * d0
                + w[l.y] * d1 * d1
                + w[l.z] * d2 * d2
                + w[l.w] * d3 * d3;
        acc += (double)s;
    }

    // wave (64-lane) shuffle reduction
    for (int off = 32; off > 0; off >>= 1)
        acc += __shfl_down(acc, off, 64);

    __shared__ double wave_sums[NTHREADS / 64];
    int lane = threadIdx.x & 63;
    int wid  = threadIdx.x >> 6;
    if (lane == 0) wave_sums[wid] = acc;
    __syncthreads();

    if (threadIdx.x == 0) {
        double t = 0.0;
        #pragma unroll
        for (int k = 0; k < NTHREADS / 64; ++k) t += wave_sums[k];
        partials[blockIdx.x] = t;
    }
}

__global__ __launch_bounds__(NTHREADS) void wmse_final_kernel(
    const double* __restrict__ partials,
    float* __restrict__ out,
    int nparts,
    double inv_n)
{
    double acc = 0.0;
    for (int i = threadIdx.x; i < nparts; i += NTHREADS)
        acc += partials[i];

    for (int off = 32; off > 0; off >>= 1)
        acc += __shfl_down(acc, off, 64);

    __shared__ double wave_sums[NTHREADS / 64];
    int lane = threadIdx.x & 63;
    int wid  = threadIdx.x >> 6;
    if (lane == 0) wave_sums[wid] = acc;
    __syncthreads();

    if (threadIdx.x == 0) {
        double t = 0.0;
        #pragma unroll
        for (int k = 0; k < NTHREADS / 64; ++k) t += wave_sums[k];
        out[0] = (float)(t * inv_n);
    }
}

extern "C" void kernel_launch(void* const* d_in, const int* in_sizes, int n_in,
                              void* d_out, int out_size, void* d_ws, size_t ws_size,
                              hipStream_t stream) {
    const float* pred    = (const float*)d_in[0];
    const int*   labels  = (const int*)d_in[1];
    const float* weights = (const float*)d_in[2];
    float* out = (float*)d_out;

    int n  = in_sizes[0];          // 33,554,432 = 2^25
    int n4 = n >> 2;               // exactly divisible

    double* partials = (double*)d_ws;  // 2048 doubles = 16 KB

    wmse_partial_kernel<<<NBLOCKS, NTHREADS, 0, stream>>>(
        (const float4*)pred, (const int4*)labels, weights, partials, n4);

    wmse_final_kernel<<<1, NTHREADS, 0, stream>>>(
        partials, out, NBLOCKS, 1.0 / (double)n);
}